// Round 1
// baseline (79.480 us; speedup 1.0000x reference)
//
#include <hip/hip_runtime.h>

// Problem constants: B=64, T=8192, L=64, NWIN=8128 = 8 * 1016
constexpr int B_SZ  = 64;
constexpr int T_SZ  = 8192;
constexpr int L_SZ  = 64;
constexpr int NWIN  = T_SZ - L_SZ;   // 8128
constexpr int NQ    = 8;             // chunks per batch (was 4) -> 512 blocks, 2/CU
constexpr int QW    = NWIN / NQ;     // 1016 windows per chunk (1016 % 4 == 0)
constexpr int STAGE = QW + L_SZ;     // 1080 floats staged per block (~4.3 KB)

// Single fused kernel: 512 blocks (B*NQ), one per (batch, chunk).
// Each block stages its x-slice in LDS, evaluates 1016 windows (4 per thread,
// one round), block-reduces to one packed u64 key
// ((float_bits(dist)<<32)|global_start — dist>=0 so u64 order == (dist, idx)
// lexicographic order, ties -> smallest index, matching np.argmin).
// Cross-block finish WITHOUT a second launch: release-store the key, agent-scope
// fetch_add on a per-batch arrival counter; the 8th arriver (old%8==7 — correct
// for ANY initial counter value, so no workspace init needed) min-reduces the 8
// keys and copies the winning 64-float window (bit-exact copy of input).
// No spin-waits: dispatch-order independent, cross-XCD safe via agent scope.
__global__ __launch_bounds__(256)
void window_match_fused(const float* __restrict__ X_in,
                        const float* __restrict__ X_out,
                        unsigned long long* __restrict__ ws_keys,
                        unsigned int* __restrict__ ws_cnt,
                        float* __restrict__ out)
{
    __shared__ float xs[STAGE + 8];            // ~4.3 KB
    __shared__ float ys[L_SZ];
    __shared__ unsigned long long wred[4];
    __shared__ int s_win;

    const int bq  = blockIdx.x;
    const int b   = bq >> 3;
    const int q   = bq & 7;
    const int tid = threadIdx.x;
    const int base = q * QW;                   // 1016*q, divisible by 4 -> float4 aligned

    // Stage x[b, base .. base+1079] via float4 (270 vec4 loads over 256 threads)
    const float4* xg  = reinterpret_cast<const float4*>(X_in + (size_t)b * T_SZ + base);
    float4*       xs4 = reinterpret_cast<float4*>(xs);
    for (int i = tid; i < STAGE / 4; i += 256)
        xs4[i] = xg[i];

    if (tid < L_SZ) ys[tid] = X_out[(size_t)b * L_SZ + tid];
    __syncthreads();

    float y[L_SZ];
    #pragma unroll
    for (int j = 0; j < L_SZ; ++j) y[j] = ys[j];

    unsigned long long best = ~0ull;

    // 256 threads x 4 windows = 1024 slots >= 1016 windows (threads 254,255 idle).
    const int s0 = 4 * tid;                    // local window start, float4-aligned
    if (s0 < QW) {
        float xv[68];
        const float4* p = reinterpret_cast<const float4*>(xs + s0);
        #pragma unroll
        for (int i = 0; i < 17; ++i) {
            float4 v = p[i];
            xv[4 * i + 0] = v.x;
            xv[4 * i + 1] = v.y;
            xv[4 * i + 2] = v.z;
            xv[4 * i + 3] = v.w;
        }
        #pragma unroll
        for (int w = 0; w < 4; ++w) {
            float d = 0.0f;
            #pragma unroll
            for (int j = 0; j < L_SZ; ++j) {
                const float t = xv[w + j] - y[j];
                d = fmaf(t, t, d);
            }
            const unsigned long long key =
                ((unsigned long long)__float_as_uint(d) << 32) |
                (unsigned int)(base + s0 + w);
            best = key < best ? key : best;
        }
    }

    // Wave (64-lane) shuffle reduce, then cross-wave via LDS
    #pragma unroll
    for (int off = 32; off > 0; off >>= 1) {
        const unsigned long long o = __shfl_down(best, off, 64);
        best = o < best ? o : best;
    }
    if ((tid & 63) == 0) wred[tid >> 6] = best;
    __syncthreads();

    if (tid == 0) {
        unsigned long long m = wred[0];
        m = wred[1] < m ? wred[1] : m;
        m = wred[2] < m ? wred[2] : m;
        m = wred[3] < m ? wred[3] : m;

        // Publish this block's key (agent scope = device-coherent across XCDs)
        __hip_atomic_store(&ws_keys[bq], m, __ATOMIC_RELEASE,
                           __HIP_MEMORY_SCOPE_AGENT);
        const unsigned int old = __hip_atomic_fetch_add(&ws_cnt[b], 1u,
                                                        __ATOMIC_ACQ_REL,
                                                        __HIP_MEMORY_SCOPE_AGENT);
        int sw = -1;
        if ((old & 7u) == 7u) {
            // Last arriver for this batch: RMW chain on ws_cnt[b] orders all 8
            // key release-stores before these acquire loads.
            unsigned long long g = __hip_atomic_load(&ws_keys[b * NQ + 0],
                                                     __ATOMIC_ACQUIRE,
                                                     __HIP_MEMORY_SCOPE_AGENT);
            #pragma unroll
            for (int qq = 1; qq < NQ; ++qq) {
                const unsigned long long o = __hip_atomic_load(&ws_keys[b * NQ + qq],
                                                               __ATOMIC_ACQUIRE,
                                                               __HIP_MEMORY_SCOPE_AGENT);
                g = o < g ? o : g;
            }
            sw = (int)(g & 0xffffffffu);
        }
        s_win = sw;
    }
    __syncthreads();

    const int s = s_win;
    if (s >= 0 && tid < L_SZ)
        out[(size_t)b * L_SZ + tid] = X_in[(size_t)b * T_SZ + s + tid];
}

extern "C" void kernel_launch(void* const* d_in, const int* in_sizes, int n_in,
                              void* d_out, int out_size, void* d_ws, size_t ws_size,
                              hipStream_t stream) {
    // Input order: feats_in (unused), X_in, feats_out (unused), X_out
    const float* X_in  = (const float*)d_in[1];
    const float* X_out = (const float*)d_in[3];
    float* out = (float*)d_out;
    unsigned long long* ws_keys = (unsigned long long*)d_ws;            // 512 * 8 B
    unsigned int* ws_cnt = (unsigned int*)((char*)d_ws + B_SZ * NQ * 8); // 64 * 4 B

    window_match_fused<<<B_SZ * NQ, 256, 0, stream>>>(X_in, X_out, ws_keys, ws_cnt, out);
}